// Round 2
// baseline (612.464 us; speedup 1.0000x reference)
//
#include <hip/hip_runtime.h>

// Self-attention B=2, S=4096, D=1024, fp32 in/out.
// Split-bf16 (hi+lo) MFMA emulation of fp32 GEMMs for the Q/K/scores path
// (softmax is near-one-hot: score errors must be << top-2 gap), plain bf16
// MFMA for V projection and PV. m97-style 128x128x32 GEMM structure with
// global_load_lds staging.
//
// Round-2 change: workspace cut to ~104 MB (was 330 MB -> suspected OOB
// core dump). Batches processed sequentially reusing buffers; Eh/El/W alias
// the scores region; P is written bf16 in-place over the fp32 scores rows.
// ws_size guard turns "workspace too small" into a clean absmax failure.

#define S_LEN 4096
#define D_DIM 1024

typedef __bf16 bf16x8 __attribute__((ext_vector_type(8)));
typedef float f32x4 __attribute__((ext_vector_type(4)));

__device__ __forceinline__ unsigned short f2bf(float x) {
  unsigned u = __float_as_uint(x);
  unsigned r = u + 0x7fffu + ((u >> 16) & 1u);  // round-to-nearest-even
  return (unsigned short)(r >> 16);
}
__device__ __forceinline__ float bf2f(unsigned short h) {
  return __uint_as_float(((unsigned)h) << 16);
}

__device__ __forceinline__ void gl_lds16(const void* g, void* l) {
  __builtin_amdgcn_global_load_lds(
      (const __attribute__((address_space(1))) void*)g,
      (__attribute__((address_space(3))) void*)l, 16, 0, 0);
}

// ---------------------------------------------------------------------------
// split_emb: fp32 -> (hi, lo) bf16 pair, elementwise, float4-vectorized.
// Grid covers exactly one batch: 4096 blocks * 256 thr * 4 floats = 4096*1024.
__launch_bounds__(256)
__global__ void split_emb(const float* __restrict__ e,
                          unsigned short* __restrict__ Eh,
                          unsigned short* __restrict__ El) {
  int i = blockIdx.x * 256 + threadIdx.x;  // float4 index
  float4 v = reinterpret_cast<const float4*>(e)[i];
  ushort4 h, l;
  h.x = f2bf(v.x); l.x = f2bf(v.x - bf2f(h.x));
  h.y = f2bf(v.y); l.y = f2bf(v.y - bf2f(h.y));
  h.z = f2bf(v.z); l.z = f2bf(v.z - bf2f(h.z));
  h.w = f2bf(v.w); l.w = f2bf(v.w - bf2f(h.w));
  reinterpret_cast<ushort4*>(Eh)[i] = h;
  reinterpret_cast<ushort4*>(El)[i] = l;
}

// ---------------------------------------------------------------------------
// prep_w: W[d][e] -> Wt[e][d], split (q,k) or plain (v). 32x32 LDS transpose.
__launch_bounds__(256)
__global__ void prep_w(const float* __restrict__ wq, const float* __restrict__ wk,
                       const float* __restrict__ wv,
                       unsigned short* __restrict__ Wth, unsigned short* __restrict__ Wtl,
                       unsigned short* __restrict__ Wvt) {
  __shared__ float tile[32][33];
  const int z = blockIdx.z;
  const float* W = (z == 0) ? wq : (z == 1) ? wk : wv;
  const int bx = blockIdx.x * 32;  // e block
  const int by = blockIdx.y * 32;  // d block
  const int tx = threadIdx.x;      // 0..31
  const int ty = threadIdx.y;      // 0..7
#pragma unroll
  for (int j = 0; j < 4; ++j)
    tile[ty + j * 8][tx] = W[(long)(by + ty + j * 8) * D_DIM + bx + tx];
  __syncthreads();
#pragma unroll
  for (int j = 0; j < 4; ++j) {
    float v = tile[tx][ty + j * 8];  // = W[by+tx][bx+ty+j*8]
    long o = (long)(bx + ty + j * 8) * D_DIM + by + tx;
    if (z < 2) {
      long oo = (long)z * (1024 * 1024) + o;  // Wq^T rows 0..1023, Wk^T rows 1024..2047
      unsigned short h = f2bf(v);
      Wth[oo] = h;
      Wtl[oo] = f2bf(v - bf2f(h));
    } else {
      Wvt[o] = f2bf(v);
    }
  }
}

// ---------------------------------------------------------------------------
// Generic NT GEMM: C[m][n] = sum_k A[m][k]*B[n][k].  BM=BN=128, BK=32,
// 4 waves, 4x4 16x16x32 fragments per wave.  SPLIT=1: A,B are (hi,lo) pairs,
// 3 MFMA products per fragment pair (fp32 emulation).
// MODE 0: split-bf16 store (Cp=hi, C2=lo)          [QK projection]
// MODE 1: fp32 store of acc*scale + maskT           [scores]
// MODE 2: plain bf16 store                          [Vt projection]
// MODE 3: fp32 store                                [output PV]
template <int SPLIT, int MODE>
__launch_bounds__(256)
__global__ void gemm_bt(const unsigned short* __restrict__ Ah,
                        const unsigned short* __restrict__ Al, int lda,
                        const unsigned short* __restrict__ Bh,
                        const unsigned short* __restrict__ Bl, int ldb,
                        void* __restrict__ Cp, int ldc,
                        unsigned short* __restrict__ C2,
                        const float* __restrict__ mask, float scale, int kIters) {
  __shared__ unsigned short lAh[128 * 32];
  __shared__ unsigned short lBh[128 * 32];
  __shared__ unsigned short lAl[SPLIT ? 128 * 32 : 8];
  __shared__ unsigned short lBl[SPLIT ? 128 * 32 : 8];

  const int t = threadIdx.x;
  const int w = t >> 6;
  const int lane = t & 63;
  const int g = lane >> 4;
  const int r = lane & 15;
  const int wm = (w >> 1) * 64;
  const int wn = (w & 1) * 64;
  const long bm = (long)blockIdx.x * 128;
  const long bn = (long)blockIdx.y * 128;

  f32x4 acc[4][4];
  const f32x4 vzero = {0.f, 0.f, 0.f, 0.f};
#pragma unroll
  for (int mi = 0; mi < 4; ++mi)
#pragma unroll
    for (int ni = 0; ni < 4; ++ni) acc[mi][ni] = vzero;

  for (int kt = 0; kt < kIters; ++kt) {
    __syncthreads();
    const long kbase = (long)kt * 32;
#pragma unroll
    for (int i = 0; i < 2; ++i) {
      // chunk c in [0,512): 16B granules of the 128x32 bf16 tile (row-major)
      int c = (i * 4 + w) * 64 + lane;
      int row = c >> 2;
      int ko = (c & 3) * 8;
      long goffA = (bm + row) * (long)lda + kbase + ko;
      long goffB = (bn + row) * (long)ldb + kbase + ko;
      int lbase = (i * 4 + w) * 512;  // wave-uniform LDS base (ushort units)
      gl_lds16(Ah + goffA, lAh + lbase);
      gl_lds16(Bh + goffB, lBh + lbase);
      if constexpr (SPLIT) {
        gl_lds16(Al + goffA, lAl + lbase);
        gl_lds16(Bl + goffB, lBl + lbase);
      }
    }
    __syncthreads();

    bf16x8 af[4], bfh[4], af2[4], bf2v[4];
#pragma unroll
    for (int mi = 0; mi < 4; ++mi) {
      int rowa = wm + mi * 16 + r;
      af[mi] = *reinterpret_cast<const bf16x8*>(&lAh[rowa * 32 + g * 8]);
      if constexpr (SPLIT)
        af2[mi] = *reinterpret_cast<const bf16x8*>(&lAl[rowa * 32 + g * 8]);
    }
#pragma unroll
    for (int ni = 0; ni < 4; ++ni) {
      int rowb = wn + ni * 16 + r;
      bfh[ni] = *reinterpret_cast<const bf16x8*>(&lBh[rowb * 32 + g * 8]);
      if constexpr (SPLIT)
        bf2v[ni] = *reinterpret_cast<const bf16x8*>(&lBl[rowb * 32 + g * 8]);
    }
#pragma unroll
    for (int mi = 0; mi < 4; ++mi)
#pragma unroll
      for (int ni = 0; ni < 4; ++ni) {
        acc[mi][ni] = __builtin_amdgcn_mfma_f32_16x16x32_bf16(af[mi], bfh[ni], acc[mi][ni], 0, 0, 0);
        if constexpr (SPLIT) {
          acc[mi][ni] = __builtin_amdgcn_mfma_f32_16x16x32_bf16(af[mi], bf2v[ni], acc[mi][ni], 0, 0, 0);
          acc[mi][ni] = __builtin_amdgcn_mfma_f32_16x16x32_bf16(af2[mi], bfh[ni], acc[mi][ni], 0, 0, 0);
        }
      }
  }

  // Epilogue. C/D layout: col = lane&15, row = 4*(lane>>4) + reg (m89-verified).
#pragma unroll
  for (int mi = 0; mi < 4; ++mi) {
#pragma unroll
    for (int ni = 0; ni < 4; ++ni) {
      long row0 = bm + wm + mi * 16 + g * 4;
      long col = bn + wn + ni * 16 + r;
#pragma unroll
      for (int q = 0; q < 4; ++q) {
        float v = acc[mi][ni][q];
        long row = row0 + q;
        if constexpr (MODE == 0) {
          unsigned short h = f2bf(v);
          ((unsigned short*)Cp)[row * (long)ldc + col] = h;
          C2[row * (long)ldc + col] = f2bf(v - bf2f(h));
        } else if constexpr (MODE == 1) {
          // scores[q_row][k_col]: add mask_filled.T = mask[k][q] (or -inf)
          float mv = mask[col * (long)S_LEN + row];
          v = v * scale;
          v = (mv == 0.0f) ? -__builtin_inff() : (v + mv);
          ((float*)Cp)[row * (long)ldc + col] = v;
        } else if constexpr (MODE == 2) {
          ((unsigned short*)Cp)[row * (long)ldc + col] = f2bf(v);
        } else {
          ((float*)Cp)[row * (long)ldc + col] = v;
        }
      }
    }
  }
}

// ---------------------------------------------------------------------------
// Row softmax, IN PLACE: reads 4096 fp32 of row `blockIdx.x`, writes 4096
// bf16 into the first half of the same row's storage. Safe: every load is
// sequenced before the first __syncthreads (via the shfl/LDS reduction deps),
// every store after the second.
__launch_bounds__(256)
__global__ void softmax_rows(float* __restrict__ Sc) {
  const long row = blockIdx.x;
  float* sr = Sc + row * (long)S_LEN;
  unsigned short* pr = (unsigned short*)sr;
  const int t = threadIdx.x;
  const int lane = t & 63, wid = t >> 6;

  float4 x[4];
  float m = -3.0e38f;
#pragma unroll
  for (int i = 0; i < 4; ++i) {
    x[i] = reinterpret_cast<const float4*>(sr)[t + i * 256];
    m = fmaxf(m, fmaxf(fmaxf(x[i].x, x[i].y), fmaxf(x[i].z, x[i].w)));
  }
#pragma unroll
  for (int o = 32; o; o >>= 1) m = fmaxf(m, __shfl_xor(m, o));
  __shared__ float redm[4];
  __shared__ float reds[4];
  if (lane == 0) redm[wid] = m;
  __syncthreads();
  m = fmaxf(fmaxf(redm[0], redm[1]), fmaxf(redm[2], redm[3]));

  float e[16];
  float s = 0.f;
#pragma unroll
  for (int i = 0; i < 4; ++i) {
    e[i * 4 + 0] = __expf(x[i].x - m);
    e[i * 4 + 1] = __expf(x[i].y - m);
    e[i * 4 + 2] = __expf(x[i].z - m);
    e[i * 4 + 3] = __expf(x[i].w - m);
    s += e[i * 4 + 0] + e[i * 4 + 1] + e[i * 4 + 2] + e[i * 4 + 3];
  }
#pragma unroll
  for (int o = 32; o; o >>= 1) s += __shfl_xor(s, o);
  if (lane == 0) reds[wid] = s;
  __syncthreads();
  s = reds[0] + reds[1] + reds[2] + reds[3];
  float inv = 1.0f / s;
#pragma unroll
  for (int i = 0; i < 4; ++i) {
    ushort4 o4;
    o4.x = f2bf(e[i * 4 + 0] * inv);
    o4.y = f2bf(e[i * 4 + 1] * inv);
    o4.z = f2bf(e[i * 4 + 2] * inv);
    o4.w = f2bf(e[i * 4 + 3] * inv);
    reinterpret_cast<ushort4*>(pr)[t + i * 256] = o4;
  }
}

// ---------------------------------------------------------------------------
extern "C" void kernel_launch(void* const* d_in, const int* in_sizes, int n_in,
                              void* d_out, int out_size, void* d_ws, size_t ws_size,
                              hipStream_t stream) {
  const float* emb  = (const float*)d_in[0];
  const float* mask = (const float*)d_in[1];
  const float* wq   = (const float*)d_in[2];
  const float* wk   = (const float*)d_in[3];
  const float* wv   = (const float*)d_in[4];
  float* out = (float*)d_out;
  char* ws = (char*)d_ws;

  // Workspace layout (bytes):
  //   region0 (per-batch QKV, reused across batches):
  //     QKh [4096][2048] bf16 : 16,777,216   (Q cols 0..1023 | K cols 1024..2047)
  //     QKl [4096][2048] bf16 : 16,777,216
  //     Vt  [1024][4096] bf16 :  8,388,608
  //   regionS: scores [4096][4096] fp32 : 67,108,864
  //     (aliased during projections: Eh 8.39M | El 8.39M | Wth 4.19M |
  //      Wtl 4.19M | Wvt 2.10M = 27.3 MB < 67.1 MB)
  const size_t SZ_QK = (size_t)4096 * 2048 * 2;
  const size_t SZ_VT = (size_t)1024 * 4096 * 2;
  const size_t SZ_SC = (size_t)4096 * 4096 * 4;
  const size_t need = 2 * SZ_QK + SZ_VT + SZ_SC;  // 109,051,904 B
  if (ws_size < need) return;  // leaves poison in d_out -> clean absmax fail (diagnostic)

  unsigned short* QKh = (unsigned short*)ws;
  unsigned short* QKl = (unsigned short*)(ws + SZ_QK);
  unsigned short* Vt  = (unsigned short*)(ws + 2 * SZ_QK);
  float* scores       = (float*)(ws + 2 * SZ_QK + SZ_VT);

  char* sc = (char*)scores;
  unsigned short* Eh  = (unsigned short*)(sc);
  unsigned short* El  = (unsigned short*)(sc + 8388608);
  unsigned short* Wth = (unsigned short*)(sc + 16777216);
  unsigned short* Wtl = (unsigned short*)(sc + 20971520);
  unsigned short* Wvt = (unsigned short*)(sc + 25165824);

  for (int b = 0; b < 2; ++b) {
    const float* embb = emb + (size_t)b * 4096 * 1024;
    float* outb = out + (size_t)b * 4096 * 1024;

    // 1) split embeddings (this batch) into bf16 hi/lo
    split_emb<<<4096, 256, 0, stream>>>(embb, Eh, El);
    // 2) transpose+split weights (recomputed per batch: they live in the
    //    scores region which batch b-1's scores overwrote)
    prep_w<<<dim3(32, 32, 3), dim3(32, 8), 0, stream>>>(wq, wk, wv, Wth, Wtl, Wvt);
    // 3) [Q|K] = emb @ [Wq|Wk]  (split-3 fp32 emulation), split-store
    gemm_bt<1, 0><<<dim3(32, 16), 256, 0, stream>>>(
        Eh, El, 1024, Wth, Wtl, 1024, (void*)QKh, 2048, QKl, nullptr, 0.f, 32);
    // 4) Vt[e][s] = Wv^T @ emb^T  (plain bf16)
    gemm_bt<0, 2><<<dim3(8, 32), 256, 0, stream>>>(
        Wvt, nullptr, 1024, Eh, nullptr, 1024, (void*)Vt, 4096, nullptr, nullptr, 0.f, 32);
    // 5) scores = (Q K^T)/32 + mask_filled^T  (split-3), fp32
    //    (overwrites the Eh/El/W aliases -- they are dead now)
    gemm_bt<1, 1><<<dim3(32, 32), 256, 0, stream>>>(
        QKh, QKl, 2048, QKh + 1024, QKl + 1024, 2048,
        (void*)scores, 4096, nullptr, mask, 0.03125f, 32);
    // 6) row softmax -> P (bf16), in place over scores rows (ld 8192 ushorts)
    softmax_rows<<<4096, 256, 0, stream>>>(scores);
    // 7) out = P @ V  (plain bf16, fp32 store)
    gemm_bt<0, 3><<<dim3(32, 8), 256, 0, stream>>>(
        (unsigned short*)scores, nullptr, 8192, Vt, nullptr, 4096,
        (void*)outb, 1024, nullptr, nullptr, 0.f, 128);
  }
}